// Round 7
// baseline (449.604 us; speedup 1.0000x reference)
//
#include <hip/hip_runtime.h>

// ProdAttention: LN -> QKV proj -> per-head top-32 of q.k^T (softmax monotone
// => select on raw sim) -> unweighted gather-sum of selected v rows -> global
// minmax-normalize + exp -> transpose -> output proj + bias.
// R22: attn geometry 16-wave/16-row -> 8-wave/8-row blocks.  Evidence: attn
// floor is a 2-way-overlapped serial chain (kb 66KB capped 2 blocks/CU; a
// block's waves lockstep through butterfly/ballot/gather latencies; setprio
// +10us proved sim scheduling matters; select op-count changes proved
// non-critical R17/R20).  kb[8][1028]=33KB => 4 blocks/CU (4x8=32 waves/CU
// unchanged), 4 phase-staggered blocks hide each other's latency, 8-wave
// barriers.  Cost: MFMA x2 (8 of 16 rows used, MfmaUtil 5.6->~11%) and k-L2
// traffic x2 (2GB vs 34TB/s L2 - not binding).  kb writes masked quad<2;
// sim rows 0..7 bit-identical => selection & output bit-identical.

#define LN_EPS 1e-5f

using half8   = __attribute__((ext_vector_type(8))) _Float16;
using half4   = __attribute__((ext_vector_type(4))) _Float16;
using float4v = __attribute__((ext_vector_type(4))) float;

__device__ __forceinline__ void gload_lds16(const void* g, void* l) {
  __builtin_amdgcn_global_load_lds(
      (const __attribute__((address_space(1))) void*)g,
      (__attribute__((address_space(3))) void*)l, 16, 0, 0);
}
__device__ __forceinline__ float4v mfma16(half8 a, half8 b, float4v c) {
  return __builtin_amdgcn_mfma_f32_16x16x32_f16(a, b, c, 0, 0, 0);
}
struct HL { _Float16 h, l; };
__device__ __forceinline__ HL split2(float x) {
  _Float16 h = (_Float16)x;
  return { h, (_Float16)(x - (float)h) };
}
// rank of this lane within mask (count of set bits strictly below my lane)
__device__ __forceinline__ int mbcnt(unsigned long long m) {
  return __builtin_amdgcn_mbcnt_hi((unsigned)(m >> 32),
         __builtin_amdgcn_mbcnt_lo((unsigned)m, 0u));
}

// ---------------- order-preserving key helpers ----------------
__device__ __forceinline__ unsigned fkey(float f) {
  unsigned u = __float_as_uint(f);
  return ((int)u < 0) ? ~u : (u | 0x80000000u);
}
__device__ __forceinline__ int enc_i(float f) {
  int i = __float_as_int(f);
  return i >= 0 ? i : (i ^ 0x7fffffff);
}
__device__ __forceinline__ float dec_i(int e) {
  return __int_as_float(e >= 0 ? e : (e ^ 0x7fffffff));
}

// ---------------- K1: LN + weight-convert + minmax-slot-init (fused) --------
// blocks 0..4095: LN row; 4096..8191: weight cvt chunk; 8192: slot init.
__global__ __launch_bounds__(256)
void prep_kernel(const float* __restrict__ x, const float* __restrict__ gamma,
                 const float* __restrict__ beta,
                 _Float16* __restrict__ xh, _Float16* __restrict__ xl,
                 const float* __restrict__ wqkv, const float* __restrict__ wout,
                 _Float16* __restrict__ wqh, _Float16* __restrict__ wql,
                 _Float16* __restrict__ woh,
                 int* __restrict__ pmin, int* __restrict__ pmax) {
  int blk = blockIdx.x, t = threadIdx.x;
  if (blk < 4096) {
    __shared__ float red[8];
    int row = blk;
    const float4* xr = (const float4*)(x + (size_t)row * 1024);
    float4 v = xr[t];
    float s  = v.x + v.y + v.z + v.w;
    float s2 = v.x*v.x + v.y*v.y + v.z*v.z + v.w*v.w;
    #pragma unroll
    for (int o = 32; o >= 1; o >>= 1) {
      s  += __shfl_xor(s,  o, 64);
      s2 += __shfl_xor(s2, o, 64);
    }
    int w = t >> 6, l = t & 63;
    if (l == 0) { red[w*2] = s; red[w*2+1] = s2; }
    __syncthreads();
    float S  = red[0] + red[2] + red[4] + red[6];
    float S2 = red[1] + red[3] + red[5] + red[7];
    float mu  = S * (1.0f/1024.0f);
    float var = S2 * (1.0f/1024.0f) - mu*mu;
    float r = rsqrtf(var + LN_EPS);
    float4 g  = ((const float4*)gamma)[t];
    float4 bb = ((const float4*)beta)[t];
    float o0 = (v.x - mu) * r * g.x + bb.x;
    float o1 = (v.y - mu) * r * g.y + bb.y;
    float o2 = (v.z - mu) * r * g.z + bb.z;
    float o3 = (v.w - mu) * r * g.w + bb.w;
    HL r0 = split2(o0), r1 = split2(o1), r2 = split2(o2), r3 = split2(o3);
    half4 hh = { r0.h, r1.h, r2.h, r3.h };
    half4 ll = { r0.l, r1.l, r2.l, r3.l };
    size_t e = (size_t)row * 1024 + t*4;
    *(half4*)(xh + e) = hh;
    *(half4*)(xl + e) = ll;
  } else if (blk < 8192) {
    size_t i4 = (size_t)(blk - 4096) * 256 + t;   // float4 index, 1M total
    if (i4 < 786432) {            // w_qkv -> hi plane (+lo for q,k rows only)
      float4 v = ((const float4*)wqkv)[i4];
      half4 hh = { (_Float16)v.x, (_Float16)v.y, (_Float16)v.z, (_Float16)v.w };
      ((half4*)wqh)[i4] = hh;
      if (i4 < 524288) {          // rows < 2048 (q,k): lo plane needed
        HL r0 = split2(v.x), r1 = split2(v.y), r2 = split2(v.z), r3 = split2(v.w);
        half4 ll = { r0.l, r1.l, r2.l, r3.l };
        ((half4*)wql)[i4] = ll;
      }
    } else {                      // w_out -> single f16 plane (1-term gemm)
      size_t off = i4 - 786432;
      float4 v = ((const float4*)wout)[off];
      half4 hh = { (_Float16)v.x, (_Float16)v.y, (_Float16)v.z, (_Float16)v.w };
      ((half4*)woh)[off] = hh;
    }
  } else {
    if (t < 64)              pmin[t]      = 0x7fffffff;
    else if (t < 128)        pmax[t - 64] = (int)0x80000000;
  }
}

// ---------------- K2: f16-split MFMA NT GEMM, 128x128 tile (QKV) ------------
// C[m][n] = sum_k A[m][k]*B[n][k].  q/k blocks (x<16): A = Ah+Al, B = Bh+Bl,
// 3 MFMA terms term-major (bit-identical to prior rounds).  v blocks
// (x>=16): single hh term (v precision not selection-critical), half
// staging.  Scatters q,k -> f16 hi/lo planes [bh][n][d]; v -> fp32.
__global__ __launch_bounds__(256)
void gemm_qkv(const _Float16* __restrict__ Ah, const _Float16* __restrict__ Al,
              const _Float16* __restrict__ Bh, const _Float16* __restrict__ Bl,
              _Float16* __restrict__ QH, _Float16* __restrict__ QL,
              _Float16* __restrict__ KH, _Float16* __restrict__ KL,
              float* __restrict__ CV) {
  __shared__ __align__(16) _Float16 lds[4 * 128 * 32];  // Ah | Al | Bh | Bl
  const int K = 1024;
  int tid = threadIdx.x, w = tid >> 6, l = tid & 63;
  int m0 = blockIdx.y * 128, n0 = blockIdx.x * 128;
  int wm = (w >> 1) * 64, wn = (w & 1) * 64;
  bool vblk = (n0 >= 2048);     // uniform per block

  const _Float16* src = (w == 0) ? Ah : (w == 1) ? Al : (w == 2) ? Bh : Bl;
  int rowbase = (w < 2) ? m0 : n0;
  _Float16* dst = lds + (size_t)w * 4096;
  int sr = l >> 2, sc = l & 3;
  bool stager = !vblk || (w & 1) == 0;   // v-blocks: only Ah (w0), Bh (w2)

  float4v acc[4][4];
  #pragma unroll
  for (int u = 0; u < 4; ++u)
    #pragma unroll
    for (int vv = 0; vv < 4; ++vv) acc[u][vv] = (float4v){0.f, 0.f, 0.f, 0.f};

  int quad = l >> 4, lo16 = l & 15;
  for (int kt = 0; kt < K; kt += 32) {
    __syncthreads();
    if (stager) {
      #pragma unroll
      for (int i = 0; i < 8; ++i) {
        int row = i * 16 + sr;
        gload_lds16(src + (size_t)(rowbase + row) * K + kt + sc * 8,
                    dst + row * 32 + sc * 8);
      }
    }
    __syncthreads();
    half8 ah[4], bh[4];
    #pragma unroll
    for (int u = 0; u < 4; ++u) {
      int mrow = wm + u * 16 + lo16;
      int nrow = wn + u * 16 + lo16;
      ah[u] = *(const half8*)&lds[        (size_t)mrow * 32 + quad * 8];
      bh[u] = *(const half8*)&lds[ 8192 + (size_t)nrow * 32 + quad * 8];
    }
    // term-major issue: 16 independent accumulators between dependent pairs
    #pragma unroll
    for (int u = 0; u < 4; ++u)
      #pragma unroll
      for (int vv = 0; vv < 4; ++vv)
        acc[u][vv] = mfma16(ah[u], bh[vv], acc[u][vv]);
    if (!vblk) {
      half8 al[4], bl[4];
      #pragma unroll
      for (int u = 0; u < 4; ++u) {
        int mrow = wm + u * 16 + lo16;
        int nrow = wn + u * 16 + lo16;
        al[u] = *(const half8*)&lds[ 4096 + (size_t)mrow * 32 + quad * 8];
        bl[u] = *(const half8*)&lds[12288 + (size_t)nrow * 32 + quad * 8];
      }
      #pragma unroll
      for (int u = 0; u < 4; ++u)
        #pragma unroll
        for (int vv = 0; vv < 4; ++vv)
          acc[u][vv] = mfma16(ah[u], bl[vv], acc[u][vv]);
      #pragma unroll
      for (int u = 0; u < 4; ++u)
        #pragma unroll
        for (int vv = 0; vv < 4; ++vv)
          acc[u][vv] = mfma16(al[u], bh[vv], acc[u][vv]);
    }
  }

  // epilogue: C row = m ((lane>>4)*4+reg), col = n (lane&15)
  #pragma unroll
  for (int u = 0; u < 4; ++u) {
    #pragma unroll
    for (int vv = 0; vv < 4; ++vv) {
      #pragma unroll
      for (int rg = 0; rg < 4; ++rg) {
        int row = m0 + wm + u * 16 + quad * 4 + rg;
        int col = n0 + wn + vv * 16 + lo16;
        float val = acc[u][vv][rg];
        int which = col >> 10, h = (col >> 6) & 15, dd = col & 63;
        int b = row >> 10, i = row & 1023;
        size_t e = ((size_t)(b * 16 + h) << 16) + ((size_t)i << 6) + dd;
        if (which == 2) { CV[e] = val; }
        else {
          HL sp = split2(val);
          if (which == 0) { QH[e] = sp.h; QL[e] = sp.l; }
          else            { KH[e] = sp.h; KL[e] = sp.l; }
        }
      }
    }
  }
}

// ---------------- K3: fused MFMA sim + top-32 select + v gather-sum ---------
// 512-thread blocks, 8 waves / 8 q-rows; kb[8][1028]=33KB -> 4 blocks/CU
// (32 waves/CU), 4 phase-staggered blocks per CU hide each other's serial
// chains (was 2 with 16-wave blocks).  Wave w: 128-col MFMA strip (k-frags
// double-buffered, setprio around MFMA cluster; 16-row MFMA carries 8 valid
// rows, kb writes masked quad<2); barrier; selects row w via prefix-seeded
// radix-2 ballot search (exact jax tie-break); float4 gather + shuffle
// reduce; per-head minmax atomics.
__global__ __launch_bounds__(512, 8)
void attn_kernel(const _Float16* __restrict__ qh, const _Float16* __restrict__ ql,
                 const _Float16* __restrict__ kh, const _Float16* __restrict__ kl,
                 const float* __restrict__ vg, float* __restrict__ xsum,
                 int* __restrict__ pmin, int* __restrict__ pmax) {
  __shared__ unsigned kb[8][1028];   // fkeys; stride 1028 breaks pow-2 banks
  __shared__ int sel[8][32];
  __shared__ float bmn[8], bmx[8];
  // XCD swizzle: all 128 row-blocks of a head on one XCD (k planes fit L2)
  int g = blockIdx.x;
  int xcd = g & 7, slot = g >> 3;
  int bh = (slot >> 7) * 8 + xcd, grp = slot & 127;
  int tid = threadIdx.x, w = tid >> 6, l = tid & 63;
  int quad = l >> 4, lo16 = l & 15;
  size_t hb = (size_t)bh << 16;

  // A-frags: q rows grp*8 .. +7 valid (lo16>=8 lanes read the next grp's
  // rows; their C rows 8-15 are discarded at the kb write)
  const _Float16* qhp = qh + hb + ((size_t)(grp * 8 + lo16) << 6);
  const _Float16* qlp = ql + hb + ((size_t)(grp * 8 + lo16) << 6);
  half8 ah0 = *(const half8*)(qhp + quad * 8);
  half8 ah1 = *(const half8*)(qhp + 32 + quad * 8);
  half8 al0 = *(const half8*)(qlp + quad * 8);
  half8 al1 = *(const half8*)(qlp + 32 + quad * 8);

  const _Float16* khp = kh + hb;
  const _Float16* klp = kl + hb;
  int jbase = w * 128;

  // double-buffered k-frag loads: prefetch tile tt+1 while computing tt
  half8 b0, b1, c0f, c1f, d0, d1, e0, e1;
  {
    size_t off = ((size_t)(jbase + lo16) << 6) + quad * 8;
    b0  = *(const half8*)(khp + off);
    b1  = *(const half8*)(khp + off + 32);
    c0f = *(const half8*)(klp + off);
    c1f = *(const half8*)(klp + off + 32);
  }
  #pragma unroll
  for (int tt = 0; tt < 8; ++tt) {
    if (tt < 7) {
      size_t off = ((size_t)(jbase + (tt + 1) * 16 + lo16) << 6) + quad * 8;
      d0 = *(const half8*)(khp + off);
      d1 = *(const half8*)(khp + off + 32);
      e0 = *(const half8*)(klp + off);
      e1 = *(const half8*)(klp + off + 32);
    }
    float4v acc = (float4v){0.f, 0.f, 0.f, 0.f};
    __builtin_amdgcn_s_setprio(1);
    acc = mfma16(ah0, b0, acc);
    acc = mfma16(ah0, c0f, acc);
    acc = mfma16(al0, b0, acc);
    acc = mfma16(ah1, b1, acc);
    acc = mfma16(ah1, c1f, acc);
    acc = mfma16(al1, b1, acc);
    __builtin_amdgcn_s_setprio(0);
    int jc = jbase + tt * 16 + lo16;
    if (quad < 2) {                // C rows 0..7 = the block's 8 q-rows
      #pragma unroll
      for (int rg = 0; rg < 4; ++rg)
        kb[quad * 4 + rg][jc] = fkey(acc[rg]);   // key-ify in VMEM shadow
    }
    b0 = d0; b1 = d1; c0f = e0; c1f = e1;
  }
  __syncthreads();

  // wave w selects row w
  unsigned ku[16];
  #pragma unroll
  for (int s = 0; s < 16; ++s) ku[s] = kb[w][s * 64 + l];

  // ---- seed: per-lane max -> wave max (UB) and min-of-lane-maxes (LB).
  // Every lane has >=1 key >= LB => count(>=LB) >= 64 => LB <= k32 <= UB.
  // k32 shares the common prefix of [LB,UB]; start radix-2 descent there.
  unsigned lmax = ku[0];
  #pragma unroll
  for (int s = 1; s < 16; ++s) lmax = (ku[s] > lmax) ? ku[s] : lmax;
  unsigned rmx = lmax, rmn = lmax;
  #pragma unroll
  for (int o = 32; o >= 1; o >>= 1) {
    unsigned tx = (unsigned)__shfl_xor((int)rmx, o, 64);
    unsigned tn = (unsigned)__shfl_xor((int)rmn, o, 64);
    rmx = (tx > rmx) ? tx : rmx;
    rmn = (tn < rmn) ? tn : rmn;
  }

  unsigned cur;
  bool exact = false;
  unsigned diff = rmx ^ rmn;
  if (diff == 0u) {
    cur = rmx;           // >=64 keys equal rmx => k32 == rmx; tie path below
  } else {
    int hbit = 31 - __builtin_clz(diff);
    unsigned mask = (hbit == 31) ? 0xffffffffu : ((2u << hbit) - 1u);
    cur = rmx & ~mask;   // common prefix of [LB,UB]; count(>=cur) >= 32
    // radix-2 descent (identical round structure to the proven search),
    // early exit at exact count 32
    for (int bit = hbit; bit >= 0; --bit) {
      unsigned T = cur | (1u << bit);
      int c = 0;
      #pragma unroll
      for (int s = 0; s < 16; ++s) c += __popcll(__ballot(ku[s] >= T));
      if (c >= 32) {
        cur = T;
        if (c == 32) { exact = true; break; }
      }
    }
  }

  int base = 0;
  if (exact) {
    // fast take: set is exactly {ku >= cur}; ascending-j compaction
    #pragma unroll
    for (int s = 0; s < 16; ++s) {
      bool take = ku[s] >= cur;
      unsigned long long mtk = __ballot(take);
      if (take) sel[w][base + mbcnt(mtk)] = s * 64 + l;
      base += __popcll(mtk);
    }
  } else {
    int gcnt = 0;
    #pragma unroll
    for (int s = 0; s < 16; ++s) gcnt += __popcll(__ballot(ku[s] > cur));
    int need = 32 - gcnt;   // ties taken lowest-j first (jax tie-break)
    int eqb = 0;
    #pragma unroll
    for (int s = 0; s < 16; ++s) {
      bool gt = ku[s] > cur;
      bool eq = ku[s] == cur;
      unsigned long long meq = __ballot(eq);
      int eqr = eqb + mbcnt(meq);
      bool take = gt || (eq && (eqr < need));
      unsigned long long mtk = __ballot(take);
      if (take) sel[w][base + mbcnt(mtk)] = s * 64 + l;
      base += __popcll(mtk);
      eqb  += __popcll(meq);
    }
  }

  // float4 gather: lane-group (l>>4) covers 8 of 32 rows, cols (l&15)*4..+3;
  // 2-step shuffle reduce -> every lane holds the full sum for cols (l&15).
  const float* vb = vg + hb;
  int lg = l >> 4, lc = (l & 15) * 4;
  float4 vacc = {0.f, 0.f, 0.f, 0.f};
  #pragma unroll
  for (int p = 0; p < 8; ++p) {
    int j = sel[w][p * 4 + lg];
    float4 t = *(const float4*)(vb + ((size_t)j << 6) + lc);
    vacc.x += t.x; vacc.y += t.y; vacc.z += t.z; vacc.w += t.w;
  }
  #pragma unroll
  for (int o = 32; o >= 16; o >>= 1) {
    vacc.x += __shfl_xor(vacc.x, o, 64);
    vacc.y += __shfl_xor(vacc.y, o, 64);
    vacc.z += __shfl_xor(vacc.z, o, 64);
    vacc.w += __shfl_xor(vacc.w, o, 64);
  }
  if (l < 16)
    *(float4*)(xsum + hb + ((size_t)(grp * 8 + w) << 6) + l * 4) = vacc;

  // block min/max -> per-head atomic slot (2 atomics/block)
  float m4 = fminf(fminf(vacc.x, vacc.y), fminf(vacc.z, vacc.w));
  float M4 = fmaxf(fmaxf(vacc.x, vacc.y), fmaxf(vacc.z, vacc.w));
  #pragma unroll
  for (int o = 8; o >= 1; o >>= 1) {
    m4 = fminf(m4, __shfl_xor(m4, o, 64));
    M4 = fmaxf(M4, __shfl_xor(M4, o, 64));
  }
  if (l == 0) { bmn[w] = m4; bmx[w] = M4; }
  __syncthreads();
  if (w == 0 && l < 8) {
    float a = bmn[l], b2 = bmx[l];
    #pragma unroll
    for (int o = 4; o >= 1; o >>= 1) {
      a  = fminf(a,  __shfl_xor(a,  o, 64));
      b2 = fmaxf(b2, __shfl_xor(b2, o, 64));
    }
    if (l == 0) {
      atomicMin(pmin + bh, enc_i(a));
      atomicMax(pmax + bh, enc_i(b2));
    }
  }
}

// ---------------- K4: minmax-norm + exp + transpose -> f16 ------------------
// Reduces the 64 per-head minmax slots at block start (512 B, L2-broadcast).
__global__ __launch_bounds__(256)
void fin_kernel(const float* __restrict__ xsum, const int* __restrict__ pmin,
                const int* __restrict__ pmax, _Float16* __restrict__ oh) {
  __shared__ float mm[2];
  int tid = threadIdx.x;
  if (tid < 64) {
    float fa = dec_i(pmin[tid]);
    float fb = dec_i(pmax[tid]);
    #pragma unroll
    for (int o = 32; o >= 1; o >>= 1) {
      fa = fminf(fa, __shfl_xor(fa, o, 64));
      fb = fmaxf(fb, __shfl_xor(fb, o, 64));
    }
    if (tid == 0) { mm[0] = fa; mm[1] = fb; }
  }
  __syncthreads();
  float mn = mm[0];
  float inv = 1.0f / (mm[1] - mn);
  int idx = blockIdx.x * 256 + tid;          // float4 index
  float4 xv = ((const float4*)xsum)[idx];
  half4 hh = { (_Float16)expf((xv.x - mn) * inv),
               (_Float16)expf((xv.y - mn) * inv),
               (_Float16)expf((xv.z - mn) * inv),
               (_Float16)expf((xv.w - mn) * inv) };
  int e0 = idx << 2;
  int bh = e0 >> 16, i = (e0 >> 6) & 1023, dd = e0 & 63;
  int b = bh >> 4, h = bh & 15;
  size_t oe = ((size_t)(b * 1024 + i) << 10) + (h << 6) + dd;
  *(half4*)(oh + oe) = hh;
}

// ---------------- K5: single-term f16 out-proj GEMM, 128x64 tile ------------
// C[m][n] = sum_k A[m][k]*B[n][k] + bias[n].  A = exp outputs in [1,e]
// (f16 error ~1e-3 at C, post-selection => safe).
__global__ __launch_bounds__(256)
void gemm_out(const _Float16* __restrict__ A, const _Float16* __restrict__ Bw,
              const float* __restrict__ bias, float* __restrict__ CO) {
  __shared__ __align__(16) _Float16 lds[192 * 32];
  const int K = 1024;
  int tid = threadIdx.x, w = tid >> 6, l = tid & 63;
  int m0 = blockIdx.y * 128, n0 = blockIdx.x * 64;
  int wm = (w >> 1) * 64, wn = (w & 1) * 32;
  int sr = l >> 2, sc = l & 3;
  int quad = l >> 4, lo16 = l & 15;

  float4v acc[4][2];
  #pragma unroll
  for (int u = 0; u < 4; ++u)
    #pragma unroll
    for (int vv = 0; vv < 2; ++vv) acc[u][vv] = (float4v){0.f, 0.f, 0.f, 0.f};

  for (int kt = 0; kt < K; kt += 32) {
    __syncthreads();
    #pragma unroll
    for (int i = 0; i < 3; ++i) {
      int row = w * 48 + i * 16 + sr;      // 0..191, each exactly once
      const _Float16* sp = (row < 128)
          ? A  + (size_t)(m0 + row) * K + kt + sc * 8
          : Bw + (size_t)(n0 + row - 128) * K + kt + sc * 8;
      gload_lds16(sp, lds + row * 32 + sc * 8);
    }
    __syncthreads();
    half8 af[4], bf[2];
    #pragma unroll
    for (int u = 0; u < 4; ++u)
      af[u] = *(const half8*)&lds[(size_t)(wm + u * 16 + lo16) * 32 + quad * 8];
    #pragma unroll
    for (int vv = 0; vv < 2; ++vv)
      bf[vv] = *(const half8*)&lds[(size_t)(128 + wn + vv * 16 + lo16) * 32
                                   + quad * 8];
    #pragma unroll
    for (int u = 0; u < 4; ++u)
      #pragma unroll
      for (int vv = 0; vv < 2; ++vv)
        acc[u][vv] = mfma16(af[u], bf[vv], acc[u][vv]);
  }

  #pragma unroll
  for (int u = 0; u < 4; ++u) {
    #pragma unroll
    for (int vv = 0; vv < 2; ++vv) {
      #pragma unroll
      for (int rg = 0; rg < 4; ++rg) {
        int row = m0 + wm + u * 16 + quad * 4 + rg;
        int col = n0 + wn + vv * 16 + lo16;
        CO[(size_t)row * 1024 + col] = acc[u][vv][rg] + bias[col];
      }
    }
  }
}

// ---------------- launch ----------------
extern "C" void kernel_launch(void* const* d_in, const int* in_sizes, int n_in,
                              void* d_out, int out_size, void* d_ws, size_t ws_size,
                              hipStream_t stream) {
  const float* x     = (const float*)d_in[0];
  const float* gamma = (const float*)d_in[1];
  const float* beta  = (const float*)d_in[2];
  const float* w_qkv = (const float*)d_in[3];
  const float* w_out = (const float*)d_in[4];
  const float* b_out = (const float*)d_in[5];

  char* B = (char*)d_ws;
  const size_t MB = 1024ull * 1024ull;
  float*    v   = (float*)B;                        // 16 MB [bh][n][d]
  _Float16* qh  = (_Float16*)(B + 16*MB);           // 8 MB each plane
  _Float16* ql  = (_Float16*)(B + 24*MB);
  _Float16* kh  = (_Float16*)(B + 32*MB);
  _Float16* kl  = (_Float16*)(B + 40*MB);
  float*    xs  = (float*)(B + 48*MB);              // 16 MB (attn output)
  _Float16* xh  = (_Float16*)(B + 48*MB);           // LN planes (dead before xs)
  _Float16* xl  = (_Float16*)(B + 56*MB);
  _Float16* woh = (_Float16*)(B + 64*MB);           // 2 MB (single plane)
  int*     pmin = (int*)(B + 66*MB);                // 64 slots
  int*     pmax = (int*)(B + 66*MB + 4096);         // 64 slots
  _Float16* wqh = (_Float16*)(B + 69*MB);           // 6 MB each
  _Float16* wql = (_Float16*)(B + 75*MB);
  _Float16* oth = qh;                               // reuse q plane after attn

  prep_kernel<<<8193, 256, 0, stream>>>(x, gamma, beta, xh, xl,
                                        w_qkv, w_out, wqh, wql, woh,
                                        pmin, pmax);
  gemm_qkv<<<dim3(24, 32), 256, 0, stream>>>(
      xh, xl, wqh, wql, qh, ql, kh, kl, v);
  attn_kernel<<<8192, 512, 0, stream>>>(qh, ql, kh, kl, v, xs, pmin, pmax);
  fin_kernel<<<4096, 256, 0, stream>>>(xs, pmin, pmax, oth);
  gemm_out<<<dim3(16, 32), 256, 0, stream>>>(oth, woh, b_out, (float*)d_out);
}

// Round 8
// 351.178 us; speedup vs baseline: 1.2803x; 1.2803x over previous
//
#include <hip/hip_runtime.h>

// ProdAttention: LN -> QKV proj -> per-head top-32 of q.k^T (softmax monotone
// => select on raw sim) -> unweighted gather-sum of selected v rows -> global
// minmax-normalize + exp -> transpose -> output proj + bias.
// R23: exact revert to R21 (best-known 355.9us).  R22's 8-wave geometry
// failed (+58% attn): phase accounting from the R21/R22 pair resolves attn
// as sim ~13.5us/gen (k-frag L2 streaming, dominant) + select ~9.8us/gen
// (fixed; R17/R20 proved op-count changes there don't move the wall).
// Deeper sim pipelining is resource-blocked: VGPR depth-2 prefetch busts
// the 64-VGPR/8-waves budget (R18 occupancy cliff), LDS k-staging needs
// wave-private buffers (16 waves x 8KB + 66KB kb >> 160KB).  attn ~186us
// is this algorithm's floor within budgets; R21 config re-anchored.

#define LN_EPS 1e-5f

using half8   = __attribute__((ext_vector_type(8))) _Float16;
using half4   = __attribute__((ext_vector_type(4))) _Float16;
using float4v = __attribute__((ext_vector_type(4))) float;

__device__ __forceinline__ void gload_lds16(const void* g, void* l) {
  __builtin_amdgcn_global_load_lds(
      (const __attribute__((address_space(1))) void*)g,
      (__attribute__((address_space(3))) void*)l, 16, 0, 0);
}
__device__ __forceinline__ float4v mfma16(half8 a, half8 b, float4v c) {
  return __builtin_amdgcn_mfma_f32_16x16x32_f16(a, b, c, 0, 0, 0);
}
struct HL { _Float16 h, l; };
__device__ __forceinline__ HL split2(float x) {
  _Float16 h = (_Float16)x;
  return { h, (_Float16)(x - (float)h) };
}
// rank of this lane within mask (count of set bits strictly below my lane)
__device__ __forceinline__ int mbcnt(unsigned long long m) {
  return __builtin_amdgcn_mbcnt_hi((unsigned)(m >> 32),
         __builtin_amdgcn_mbcnt_lo((unsigned)m, 0u));
}

// ---------------- order-preserving key helpers ----------------
__device__ __forceinline__ unsigned fkey(float f) {
  unsigned u = __float_as_uint(f);
  return ((int)u < 0) ? ~u : (u | 0x80000000u);
}
__device__ __forceinline__ int enc_i(float f) {
  int i = __float_as_int(f);
  return i >= 0 ? i : (i ^ 0x7fffffff);
}
__device__ __forceinline__ float dec_i(int e) {
  return __int_as_float(e >= 0 ? e : (e ^ 0x7fffffff));
}

// ---------------- K1: LN + weight-convert + minmax-slot-init (fused) --------
// blocks 0..4095: LN row; 4096..8191: weight cvt chunk; 8192: slot init.
__global__ __launch_bounds__(256)
void prep_kernel(const float* __restrict__ x, const float* __restrict__ gamma,
                 const float* __restrict__ beta,
                 _Float16* __restrict__ xh, _Float16* __restrict__ xl,
                 const float* __restrict__ wqkv, const float* __restrict__ wout,
                 _Float16* __restrict__ wqh, _Float16* __restrict__ wql,
                 _Float16* __restrict__ woh,
                 int* __restrict__ pmin, int* __restrict__ pmax) {
  int blk = blockIdx.x, t = threadIdx.x;
  if (blk < 4096) {
    __shared__ float red[8];
    int row = blk;
    const float4* xr = (const float4*)(x + (size_t)row * 1024);
    float4 v = xr[t];
    float s  = v.x + v.y + v.z + v.w;
    float s2 = v.x*v.x + v.y*v.y + v.z*v.z + v.w*v.w;
    #pragma unroll
    for (int o = 32; o >= 1; o >>= 1) {
      s  += __shfl_xor(s,  o, 64);
      s2 += __shfl_xor(s2, o, 64);
    }
    int w = t >> 6, l = t & 63;
    if (l == 0) { red[w*2] = s; red[w*2+1] = s2; }
    __syncthreads();
    float S  = red[0] + red[2] + red[4] + red[6];
    float S2 = red[1] + red[3] + red[5] + red[7];
    float mu  = S * (1.0f/1024.0f);
    float var = S2 * (1.0f/1024.0f) - mu*mu;
    float r = rsqrtf(var + LN_EPS);
    float4 g  = ((const float4*)gamma)[t];
    float4 bb = ((const float4*)beta)[t];
    float o0 = (v.x - mu) * r * g.x + bb.x;
    float o1 = (v.y - mu) * r * g.y + bb.y;
    float o2 = (v.z - mu) * r * g.z + bb.z;
    float o3 = (v.w - mu) * r * g.w + bb.w;
    HL r0 = split2(o0), r1 = split2(o1), r2 = split2(o2), r3 = split2(o3);
    half4 hh = { r0.h, r1.h, r2.h, r3.h };
    half4 ll = { r0.l, r1.l, r2.l, r3.l };
    size_t e = (size_t)row * 1024 + t*4;
    *(half4*)(xh + e) = hh;
    *(half4*)(xl + e) = ll;
  } else if (blk < 8192) {
    size_t i4 = (size_t)(blk - 4096) * 256 + t;   // float4 index, 1M total
    if (i4 < 786432) {            // w_qkv -> hi plane (+lo for q,k rows only)
      float4 v = ((const float4*)wqkv)[i4];
      half4 hh = { (_Float16)v.x, (_Float16)v.y, (_Float16)v.z, (_Float16)v.w };
      ((half4*)wqh)[i4] = hh;
      if (i4 < 524288) {          // rows < 2048 (q,k): lo plane needed
        HL r0 = split2(v.x), r1 = split2(v.y), r2 = split2(v.z), r3 = split2(v.w);
        half4 ll = { r0.l, r1.l, r2.l, r3.l };
        ((half4*)wql)[i4] = ll;
      }
    } else {                      // w_out -> single f16 plane (1-term gemm)
      size_t off = i4 - 786432;
      float4 v = ((const float4*)wout)[off];
      half4 hh = { (_Float16)v.x, (_Float16)v.y, (_Float16)v.z, (_Float16)v.w };
      ((half4*)woh)[off] = hh;
    }
  } else {
    if (t < 64)              pmin[t]      = 0x7fffffff;
    else if (t < 128)        pmax[t - 64] = (int)0x80000000;
  }
}

// ---------------- K2: f16-split MFMA NT GEMM, 128x128 tile (QKV) ------------
// C[m][n] = sum_k A[m][k]*B[n][k].  q/k blocks (x<16): A = Ah+Al, B = Bh+Bl,
// 3 MFMA terms term-major (bit-identical to prior rounds).  v blocks
// (x>=16): single hh term (v precision not selection-critical), half
// staging.  Scatters q,k -> f16 hi/lo planes [bh][n][d]; v -> fp32.
__global__ __launch_bounds__(256)
void gemm_qkv(const _Float16* __restrict__ Ah, const _Float16* __restrict__ Al,
              const _Float16* __restrict__ Bh, const _Float16* __restrict__ Bl,
              _Float16* __restrict__ QH, _Float16* __restrict__ QL,
              _Float16* __restrict__ KH, _Float16* __restrict__ KL,
              float* __restrict__ CV) {
  __shared__ __align__(16) _Float16 lds[4 * 128 * 32];  // Ah | Al | Bh | Bl
  const int K = 1024;
  int tid = threadIdx.x, w = tid >> 6, l = tid & 63;
  int m0 = blockIdx.y * 128, n0 = blockIdx.x * 128;
  int wm = (w >> 1) * 64, wn = (w & 1) * 64;
  bool vblk = (n0 >= 2048);     // uniform per block

  const _Float16* src = (w == 0) ? Ah : (w == 1) ? Al : (w == 2) ? Bh : Bl;
  int rowbase = (w < 2) ? m0 : n0;
  _Float16* dst = lds + (size_t)w * 4096;
  int sr = l >> 2, sc = l & 3;
  bool stager = !vblk || (w & 1) == 0;   // v-blocks: only Ah (w0), Bh (w2)

  float4v acc[4][4];
  #pragma unroll
  for (int u = 0; u < 4; ++u)
    #pragma unroll
    for (int vv = 0; vv < 4; ++vv) acc[u][vv] = (float4v){0.f, 0.f, 0.f, 0.f};

  int quad = l >> 4, lo16 = l & 15;
  for (int kt = 0; kt < K; kt += 32) {
    __syncthreads();
    if (stager) {
      #pragma unroll
      for (int i = 0; i < 8; ++i) {
        int row = i * 16 + sr;
        gload_lds16(src + (size_t)(rowbase + row) * K + kt + sc * 8,
                    dst + row * 32 + sc * 8);
      }
    }
    __syncthreads();
    half8 ah[4], bh[4];
    #pragma unroll
    for (int u = 0; u < 4; ++u) {
      int mrow = wm + u * 16 + lo16;
      int nrow = wn + u * 16 + lo16;
      ah[u] = *(const half8*)&lds[        (size_t)mrow * 32 + quad * 8];
      bh[u] = *(const half8*)&lds[ 8192 + (size_t)nrow * 32 + quad * 8];
    }
    // term-major issue: 16 independent accumulators between dependent pairs
    #pragma unroll
    for (int u = 0; u < 4; ++u)
      #pragma unroll
      for (int vv = 0; vv < 4; ++vv)
        acc[u][vv] = mfma16(ah[u], bh[vv], acc[u][vv]);
    if (!vblk) {
      half8 al[4], bl[4];
      #pragma unroll
      for (int u = 0; u < 4; ++u) {
        int mrow = wm + u * 16 + lo16;
        int nrow = wn + u * 16 + lo16;
        al[u] = *(const half8*)&lds[ 4096 + (size_t)mrow * 32 + quad * 8];
        bl[u] = *(const half8*)&lds[12288 + (size_t)nrow * 32 + quad * 8];
      }
      #pragma unroll
      for (int u = 0; u < 4; ++u)
        #pragma unroll
        for (int vv = 0; vv < 4; ++vv)
          acc[u][vv] = mfma16(ah[u], bl[vv], acc[u][vv]);
      #pragma unroll
      for (int u = 0; u < 4; ++u)
        #pragma unroll
        for (int vv = 0; vv < 4; ++vv)
          acc[u][vv] = mfma16(al[u], bh[vv], acc[u][vv]);
    }
  }

  // epilogue: C row = m ((lane>>4)*4+reg), col = n (lane&15)
  #pragma unroll
  for (int u = 0; u < 4; ++u) {
    #pragma unroll
    for (int vv = 0; vv < 4; ++vv) {
      #pragma unroll
      for (int rg = 0; rg < 4; ++rg) {
        int row = m0 + wm + u * 16 + quad * 4 + rg;
        int col = n0 + wn + vv * 16 + lo16;
        float val = acc[u][vv][rg];
        int which = col >> 10, h = (col >> 6) & 15, dd = col & 63;
        int b = row >> 10, i = row & 1023;
        size_t e = ((size_t)(b * 16 + h) << 16) + ((size_t)i << 6) + dd;
        if (which == 2) { CV[e] = val; }
        else {
          HL sp = split2(val);
          if (which == 0) { QH[e] = sp.h; QL[e] = sp.l; }
          else            { KH[e] = sp.h; KL[e] = sp.l; }
        }
      }
    }
  }
}

// ---------------- K3: fused MFMA sim + top-32 select + v gather-sum ---------
// 1024-thread blocks (16 waves share 66KB key LDS -> 2 blocks/CU = 32
// waves/CU; launch_bounds(...,8) keeps SGPR bounded).  Wave w: 64-col MFMA
// strip (k-frags double-buffered, setprio around MFMA cluster); barrier;
// selects row w via prefix-seeded radix-2 ballot search (exact jax
// tie-break); float4 gather + shuffle reduce; per-head minmax atomics.
__global__ __launch_bounds__(1024, 8)
void attn_kernel(const _Float16* __restrict__ qh, const _Float16* __restrict__ ql,
                 const _Float16* __restrict__ kh, const _Float16* __restrict__ kl,
                 const float* __restrict__ vg, float* __restrict__ xsum,
                 int* __restrict__ pmin, int* __restrict__ pmax) {
  __shared__ unsigned kb[16][1028];  // fkeys; stride 1028: writes 2-way (free)
  __shared__ int sel[16][32];
  __shared__ float bmn[16], bmx[16];
  // XCD swizzle: all 64 row-blocks of a head on one XCD (k planes fit L2)
  int g = blockIdx.x;
  int xcd = g & 7, slot = g >> 3;
  int bh = (slot >> 6) * 8 + xcd, grp = slot & 63;
  int tid = threadIdx.x, w = tid >> 6, l = tid & 63;
  int quad = l >> 4, lo16 = l & 15;
  size_t hb = (size_t)bh << 16;

  // A-frags: q rows grp*16..+15 (same for all 16 waves; L1 broadcast)
  const _Float16* qhp = qh + hb + ((size_t)(grp * 16 + lo16) << 6);
  const _Float16* qlp = ql + hb + ((size_t)(grp * 16 + lo16) << 6);
  half8 ah0 = *(const half8*)(qhp + quad * 8);
  half8 ah1 = *(const half8*)(qhp + 32 + quad * 8);
  half8 al0 = *(const half8*)(qlp + quad * 8);
  half8 al1 = *(const half8*)(qlp + 32 + quad * 8);

  const _Float16* khp = kh + hb;
  const _Float16* klp = kl + hb;
  int jbase = w * 64;

  // double-buffered k-frag loads: prefetch tile tt+1 while computing tt
  half8 b0, b1, c0f, c1f, d0, d1, e0, e1;
  {
    size_t off = ((size_t)(jbase + lo16) << 6) + quad * 8;
    b0  = *(const half8*)(khp + off);
    b1  = *(const half8*)(khp + off + 32);
    c0f = *(const half8*)(klp + off);
    c1f = *(const half8*)(klp + off + 32);
  }
  #pragma unroll
  for (int tt = 0; tt < 4; ++tt) {
    if (tt < 3) {
      size_t off = ((size_t)(jbase + (tt + 1) * 16 + lo16) << 6) + quad * 8;
      d0 = *(const half8*)(khp + off);
      d1 = *(const half8*)(khp + off + 32);
      e0 = *(const half8*)(klp + off);
      e1 = *(const half8*)(klp + off + 32);
    }
    float4v acc = (float4v){0.f, 0.f, 0.f, 0.f};
    __builtin_amdgcn_s_setprio(1);
    acc = mfma16(ah0, b0, acc);
    acc = mfma16(ah0, c0f, acc);
    acc = mfma16(al0, b0, acc);
    acc = mfma16(ah1, b1, acc);
    acc = mfma16(ah1, c1f, acc);
    acc = mfma16(al1, b1, acc);
    __builtin_amdgcn_s_setprio(0);
    int jc = jbase + tt * 16 + lo16;
    #pragma unroll
    for (int rg = 0; rg < 4; ++rg)
      kb[quad * 4 + rg][jc] = fkey(acc[rg]);   // key-ify in VMEM shadow
    b0 = d0; b1 = d1; c0f = e0; c1f = e1;
  }
  __syncthreads();

  // wave w selects row w
  unsigned ku[16];
  #pragma unroll
  for (int s = 0; s < 16; ++s) ku[s] = kb[w][s * 64 + l];

  // ---- seed: per-lane max -> wave max (UB) and min-of-lane-maxes (LB).
  // Every lane has >=1 key >= LB => count(>=LB) >= 64 => LB <= k32 <= UB.
  // k32 shares the common prefix of [LB,UB]; start radix-2 descent there.
  unsigned lmax = ku[0];
  #pragma unroll
  for (int s = 1; s < 16; ++s) lmax = (ku[s] > lmax) ? ku[s] : lmax;
  unsigned rmx = lmax, rmn = lmax;
  #pragma unroll
  for (int o = 32; o >= 1; o >>= 1) {
    unsigned tx = (unsigned)__shfl_xor((int)rmx, o, 64);
    unsigned tn = (unsigned)__shfl_xor((int)rmn, o, 64);
    rmx = (tx > rmx) ? tx : rmx;
    rmn = (tn < rmn) ? tn : rmn;
  }

  unsigned cur;
  bool exact = false;
  unsigned diff = rmx ^ rmn;
  if (diff == 0u) {
    cur = rmx;           // >=64 keys equal rmx => k32 == rmx; tie path below
  } else {
    int hbit = 31 - __builtin_clz(diff);
    unsigned mask = (hbit == 31) ? 0xffffffffu : ((2u << hbit) - 1u);
    cur = rmx & ~mask;   // common prefix of [LB,UB]; count(>=cur) >= 32
    // radix-2 descent (identical round structure to the proven search),
    // early exit at exact count 32
    for (int bit = hbit; bit >= 0; --bit) {
      unsigned T = cur | (1u << bit);
      int c = 0;
      #pragma unroll
      for (int s = 0; s < 16; ++s) c += __popcll(__ballot(ku[s] >= T));
      if (c >= 32) {
        cur = T;
        if (c == 32) { exact = true; break; }
      }
    }
  }

  int base = 0;
  if (exact) {
    // fast take: set is exactly {ku >= cur}; ascending-j compaction
    #pragma unroll
    for (int s = 0; s < 16; ++s) {
      bool take = ku[s] >= cur;
      unsigned long long mtk = __ballot(take);
      if (take) sel[w][base + mbcnt(mtk)] = s * 64 + l;
      base += __popcll(mtk);
    }
  } else {
    int gcnt = 0;
    #pragma unroll
    for (int s = 0; s < 16; ++s) gcnt += __popcll(__ballot(ku[s] > cur));
    int need = 32 - gcnt;   // ties taken lowest-j first (jax tie-break)
    int eqb = 0;
    #pragma unroll
    for (int s = 0; s < 16; ++s) {
      bool gt = ku[s] > cur;
      bool eq = ku[s] == cur;
      unsigned long long meq = __ballot(eq);
      int eqr = eqb + mbcnt(meq);
      bool take = gt || (eq && (eqr < need));
      unsigned long long mtk = __ballot(take);
      if (take) sel[w][base + mbcnt(mtk)] = s * 64 + l;
      base += __popcll(mtk);
      eqb  += __popcll(meq);
    }
  }

  // float4 gather: lane-group (l>>4) covers 8 of 32 rows, cols (l&15)*4..+3;
  // 2-step shuffle reduce -> every lane holds the full sum for cols (l&15).
  const float* vb = vg + hb;
  int lg = l >> 4, lc = (l & 15) * 4;
  float4 vacc = {0.f, 0.f, 0.f, 0.f};
  #pragma unroll
  for (int p = 0; p < 8; ++p) {
    int j = sel[w][p * 4 + lg];
    float4 t = *(const float4*)(vb + ((size_t)j << 6) + lc);
    vacc.x += t.x; vacc.y += t.y; vacc.z += t.z; vacc.w += t.w;
  }
  #pragma unroll
  for (int o = 32; o >= 16; o >>= 1) {
    vacc.x += __shfl_xor(vacc.x, o, 64);
    vacc.y += __shfl_xor(vacc.y, o, 64);
    vacc.z += __shfl_xor(vacc.z, o, 64);
    vacc.w += __shfl_xor(vacc.w, o, 64);
  }
  if (l < 16)
    *(float4*)(xsum + hb + ((size_t)(grp * 16 + w) << 6) + l * 4) = vacc;

  // block min/max -> per-head atomic slot (2 atomics/block, 64-deep chains)
  float m4 = fminf(fminf(vacc.x, vacc.y), fminf(vacc.z, vacc.w));
  float M4 = fmaxf(fmaxf(vacc.x, vacc.y), fmaxf(vacc.z, vacc.w));
  #pragma unroll
  for (int o = 8; o >= 1; o >>= 1) {
    m4 = fminf(m4, __shfl_xor(m4, o, 64));
    M4 = fmaxf(M4, __shfl_xor(M4, o, 64));
  }
  if (l == 0) { bmn[w] = m4; bmx[w] = M4; }
  __syncthreads();
  if (w == 0 && l < 16) {
    float a = bmn[l], b2 = bmx[l];
    #pragma unroll
    for (int o = 8; o >= 1; o >>= 1) {
      a  = fminf(a,  __shfl_xor(a,  o, 64));
      b2 = fmaxf(b2, __shfl_xor(b2, o, 64));
    }
    if (l == 0) {
      atomicMin(pmin + bh, enc_i(a));
      atomicMax(pmax + bh, enc_i(b2));
    }
  }
}

// ---------------- K4: minmax-norm + exp + transpose -> f16 ------------------
// Reduces the 64 per-head minmax slots at block start (512 B, L2-broadcast).
__global__ __launch_bounds__(256)
void fin_kernel(const float* __restrict__ xsum, const int* __restrict__ pmin,
                const int* __restrict__ pmax, _Float16* __restrict__ oh) {
  __shared__ float mm[2];
  int tid = threadIdx.x;
  if (tid < 64) {
    float fa = dec_i(pmin[tid]);
    float fb = dec_i(pmax[tid]);
    #pragma unroll
    for (int o = 32; o >= 1; o >>= 1) {
      fa = fminf(fa, __shfl_xor(fa, o, 64));
      fb = fmaxf(fb, __shfl_xor(fb, o, 64));
    }
    if (tid == 0) { mm[0] = fa; mm[1] = fb; }
  }
  __syncthreads();
  float mn = mm[0];
  float inv = 1.0f / (mm[1] - mn);
  int idx = blockIdx.x * 256 + tid;          // float4 index
  float4 xv = ((const float4*)xsum)[idx];
  half4 hh = { (_Float16)expf((xv.x - mn) * inv),
               (_Float16)expf((xv.y - mn) * inv),
               (_Float16)expf((xv.z - mn) * inv),
               (_Float16)expf((xv.w - mn) * inv) };
  int e0 = idx << 2;
  int bh = e0 >> 16, i = (e0 >> 6) & 1023, dd = e0 & 63;
  int b = bh >> 4, h = bh & 15;
  size_t oe = ((size_t)(b * 1024 + i) << 10) + (h << 6) + dd;
  *(half4*)(oh + oe) = hh;
}

// ---------------- K5: single-term f16 out-proj GEMM, 128x64 tile ------------
// C[m][n] = sum_k A[m][k]*B[n][k] + bias[n].  A = exp outputs in [1,e]
// (f16 error ~1e-3 at C, post-selection => safe).
__global__ __launch_bounds__(256)
void gemm_out(const _Float16* __restrict__ A, const _Float16* __restrict__ Bw,
              const float* __restrict__ bias, float* __restrict__ CO) {
  __shared__ __align__(16) _Float16 lds[192 * 32];
  const int K = 1024;
  int tid = threadIdx.x, w = tid >> 6, l = tid & 63;
  int m0 = blockIdx.y * 128, n0 = blockIdx.x * 64;
  int wm = (w >> 1) * 64, wn = (w & 1) * 32;
  int sr = l >> 2, sc = l & 3;
  int quad = l >> 4, lo16 = l & 15;

  float4v acc[4][2];
  #pragma unroll
  for (int u = 0; u < 4; ++u)
    #pragma unroll
    for (int vv = 0; vv < 2; ++vv) acc[u][vv] = (float4v){0.f, 0.f, 0.f, 0.f};

  for (int kt = 0; kt < K; kt += 32) {
    __syncthreads();
    #pragma unroll
    for (int i = 0; i < 3; ++i) {
      int row = w * 48 + i * 16 + sr;      // 0..191, each exactly once
      const _Float16* sp = (row < 128)
          ? A  + (size_t)(m0 + row) * K + kt + sc * 8
          : Bw + (size_t)(n0 + row - 128) * K + kt + sc * 8;
      gload_lds16(sp, lds + row * 32 + sc * 8);
    }
    __syncthreads();
    half8 af[4], bf[2];
    #pragma unroll
    for (int u = 0; u < 4; ++u)
      af[u] = *(const half8*)&lds[(size_t)(wm + u * 16 + lo16) * 32 + quad * 8];
    #pragma unroll
    for (int vv = 0; vv < 2; ++vv)
      bf[vv] = *(const half8*)&lds[(size_t)(128 + wn + vv * 16 + lo16) * 32
                                   + quad * 8];
    #pragma unroll
    for (int u = 0; u < 4; ++u)
      #pragma unroll
      for (int vv = 0; vv < 2; ++vv)
        acc[u][vv] = mfma16(af[u], bf[vv], acc[u][vv]);
  }

  #pragma unroll
  for (int u = 0; u < 4; ++u) {
    #pragma unroll
    for (int vv = 0; vv < 2; ++vv) {
      #pragma unroll
      for (int rg = 0; rg < 4; ++rg) {
        int row = m0 + wm + u * 16 + quad * 4 + rg;
        int col = n0 + wn + vv * 16 + lo16;
        CO[(size_t)row * 1024 + col] = acc[u][vv][rg] + bias[col];
      }
    }
  }
}

// ---------------- launch ----------------
extern "C" void kernel_launch(void* const* d_in, const int* in_sizes, int n_in,
                              void* d_out, int out_size, void* d_ws, size_t ws_size,
                              hipStream_t stream) {
  const float* x     = (const float*)d_in[0];
  const float* gamma = (const float*)d_in[1];
  const float* beta  = (const float*)d_in[2];
  const float* w_qkv = (const float*)d_in[3];
  const float* w_out = (const float*)d_in[4];
  const float* b_out = (const float*)d_in[5];

  char* B = (char*)d_ws;
  const size_t MB = 1024ull * 1024ull;
  float*    v   = (float*)B;                        // 16 MB [bh][n][d]
  _Float16* qh  = (_Float16*)(B + 16*MB);           // 8 MB each plane
  _Float16* ql  = (_Float16*)(B + 24*MB);
  _Float16* kh  = (_Float16*)(B + 32*MB);
  _Float16* kl  = (_Float16*)(B + 40*MB);
  float*    xs  = (float*)(B + 48*MB);              // 16 MB (attn output)
  _Float16* xh  = (_Float16*)(B + 48*MB);           // LN planes (dead before xs)
  _Float16* xl  = (_Float16*)(B + 56*MB);
  _Float16* woh = (_Float16*)(B + 64*MB);           // 2 MB (single plane)
  int*     pmin = (int*)(B + 66*MB);                // 64 slots
  int*     pmax = (int*)(B + 66*MB + 4096);         // 64 slots
  _Float16* wqh = (_Float16*)(B + 69*MB);           // 6 MB each
  _Float16* wql = (_Float16*)(B + 75*MB);
  _Float16* oth = qh;                               // reuse q plane after attn

  prep_kernel<<<8193, 256, 0, stream>>>(x, gamma, beta, xh, xl,
                                        w_qkv, w_out, wqh, wql, woh,
                                        pmin, pmax);
  gemm_qkv<<<dim3(24, 32), 256, 0, stream>>>(
      xh, xl, wqh, wql, qh, ql, kh, kl, v);
  attn_kernel<<<4096, 1024, 0, stream>>>(qh, ql, kh, kl, v, xs, pmin, pmax);
  fin_kernel<<<4096, 256, 0, stream>>>(xs, pmin, pmax, oth);
  gemm_out<<<dim3(16, 32), 256, 0, stream>>>(oth, woh, b_out, (float*)d_out);
}